// Round 1
// baseline (225.848 us; speedup 1.0000x reference)
//
#include <hip/hip_runtime.h>
#include <hip/hip_bf16.h>
#include <math.h>

// Problem constants
#define BB   32
#define HH   40
#define WW   256
#define NF   40          // FREQ
#define H1N  36
#define W1N  252
#define KCNN 580608      // 64*36*252
#define KPW  192         // k per wave (6 chunks x 32); 3024 waves * 192 == KCNN exactly

typedef __attribute__((ext_vector_type(8))) short bf16x8;   // 8 bf16 = 4 VGPRs
typedef __attribute__((ext_vector_type(4))) float f32x4;    // MFMA C/D

static __device__ __forceinline__ unsigned short f2bf(float v) {
    __hip_bfloat16 h = __float2bfloat16(v);
    return *(unsigned short*)&h;
}

static __device__ __forceinline__ bf16x8 packbf(float4 lo, float4 hi) {
    bf16x8 r;
    r[0] = (short)f2bf(lo.x); r[1] = (short)f2bf(lo.y);
    r[2] = (short)f2bf(lo.z); r[3] = (short)f2bf(lo.w);
    r[4] = (short)f2bf(hi.x); r[5] = (short)f2bf(hi.y);
    r[6] = (short)f2bf(hi.z); r[7] = (short)f2bf(hi.w);
    return r;
}

// ---------------- K0: w1 repack f32->bf16 [tap][c1][c0]; also zero gacc + mean slot ------
__global__ void k0_prep_w1(const float* __restrict__ w1, unsigned short* __restrict__ w1c,
                           float* __restrict__ gacc, float* __restrict__ out) {
    int o = blockIdx.x * 256 + threadIdx.x;   // 72*256 = 18432 = 9*64*32
    int c0  = o & 31;
    int c1  = (o >> 5) & 63;
    int tap = o >> 11;                        // 0..8
    w1c[o] = f2bf(w1[(c1 * 32 + c0) * 9 + tap]);
    if (blockIdx.x == 0) {                    // fold the two memsets into this dispatch
        for (int p = threadIdx.x; p < 1280; p += 256) gacc[p] = 0.0f;
        if (threadIdx.x == 0) out[51200] = 0.0f;
    }
}

// ---------------- K1: fused conv0(relu) + conv1(relu) via bf16 MFMA -> x (bf16) --------
// grid (4 jt, 9 it, 32 b), block 256 (4 waves). Wave w owns output row i0+w.
// Epilogue now stages the 64x4x64 output tile in LDS (reusing ins/y0T space, dead after
// the tap loop) and writes coalesced 8B runs instead of 64 scattered 2B stores/thread.
__global__ __launch_bounds__(256) void k1_conv(
        const float* __restrict__ inp, const float* __restrict__ w0,
        const float* __restrict__ b0, const unsigned short* __restrict__ w1c,
        const float* __restrict__ b1, unsigned short* __restrict__ xbf) {
    __shared__ __align__(16) char smem[33856];
    float* ins = (float*)smem;                              // 544*4  = 2176 B
    unsigned short* y0T = (unsigned short*)(smem + 2176);   // 396*40*2 = 31680 B
    unsigned short* stg = (unsigned short*)smem;            // epilogue reuse: 32768 B

    const int jt = blockIdx.x;        // j0 = 64*jt
    const int it = blockIdx.y;        // i0 = 4*it
    const int b  = blockIdx.z;
    const int i0 = it * 4;
    const int j0 = jt * 64;
    const int tid = threadIdx.x;

    // ---- stage input rows i0..i0+7, cols j0..j0+67 ----
    for (int s = tid; s < 544; s += 256) {
        int r = s / 68, c = s - r * 68;
        int gc = j0 + c;
        ins[s] = (gc < WW) ? inp[(b * HH + i0 + r) * WW + gc] : 0.0f;
    }
    __syncthreads();

    // ---- conv0 -> y0T bf16 [pos][c0 (pad 40)] ----
    {
        const int c0 = tid & 31;
        const int pg = tid >> 5;      // 0..7
        float wreg[9];
        #pragma unroll
        for (int k = 0; k < 9; ++k) wreg[k] = w0[c0 * 9 + k];
        const float bias = b0[c0];
        for (int it2 = 0; it2 < 50; ++it2) {
            int pos = it2 * 8 + pg;   // 0..399
            if (pos < 396) {
                int r   = pos / 66;
                int col = pos - r * 66;
                float v = 0.0f;
                if (j0 + col < 254) {     // valid conv0 output col
                    float a = bias;
                    #pragma unroll
                    for (int ki = 0; ki < 3; ++ki)
                        #pragma unroll
                        for (int kj = 0; kj < 3; ++kj)
                            a = fmaf(ins[(r + ki) * 68 + col + kj], wreg[ki * 3 + kj], a);
                    v = fmaxf(a, 0.0f);
                }
                y0T[pos * 40 + c0] = f2bf(v);
            }
        }
    }
    __syncthreads();

    // ---- conv1: 9 tap-GEMMs, K=32(c0). A = w1c (global, L2-hot), B = y0T (LDS) ----
    const int w    = tid >> 6;        // wave id -> output row i0+w
    const int lane = tid & 63;
    const int l15  = lane & 15;
    const int quad = lane >> 4;

    float biasr[4][4];                // [mt][reg]
    #pragma unroll
    for (int mt = 0; mt < 4; ++mt)
        #pragma unroll
        for (int rg = 0; rg < 4; ++rg)
            biasr[mt][rg] = b1[mt * 16 + quad * 4 + rg];

    f32x4 acc[4][4];                  // [mt(ch)][nt(pos)]
    #pragma unroll
    for (int mt = 0; mt < 4; ++mt)
        #pragma unroll
        for (int nt = 0; nt < 4; ++nt)
            acc[mt][nt] = (f32x4){0.f, 0.f, 0.f, 0.f};

    #pragma unroll
    for (int ki = 0; ki < 3; ++ki) {
        #pragma unroll
        for (int kj = 0; kj < 3; ++kj) {
            const int tap = ki * 3 + kj;
            bf16x8 af[4], bfr[4];
            #pragma unroll
            for (int mt = 0; mt < 4; ++mt)   // A[m=c1][k=c0]
                af[mt] = *(const bf16x8*)(w1c + ((tap * 64 + mt * 16 + l15) * 32 + quad * 8));
            #pragma unroll
            for (int nt = 0; nt < 4; ++nt)   // B[k=c0][n=pos]
                bfr[nt] = *(const bf16x8*)(y0T + (((w + ki) * 66 + nt * 16 + l15 + kj) * 40 + quad * 8));
            #pragma unroll
            for (int mt = 0; mt < 4; ++mt)
                #pragma unroll
                for (int nt = 0; nt < 4; ++nt)
                    acc[mt][nt] = __builtin_amdgcn_mfma_f32_16x16x32_bf16(
                        af[mt], bfr[nt], acc[mt][nt], 0, 0, 0);
        }
    }

    // ---- epilogue: relu(x+b1) -> LDS tile [c1][w][j], j rotated by 16*quad(c1) to keep
    //      the ds_write_b16 bank-conflict-free while preserving 4-short read contiguity ----
    __syncthreads();                  // all waves done reading y0T before aliasing as stg
    #pragma unroll
    for (int mt = 0; mt < 4; ++mt)
        #pragma unroll
        for (int nt = 0; nt < 4; ++nt)
            #pragma unroll
            for (int rg = 0; rg < 4; ++rg) {
                int c1 = mt * 16 + quad * 4 + rg;
                int j  = nt * 16 + l15;
                int jr = (j + (((c1 >> 2) & 3) << 4)) & 63;
                float v = fmaxf(acc[mt][nt][rg] + biasr[mt][rg], 0.0f);
                stg[(c1 * 4 + w) * 64 + jr] = f2bf(v);
            }
    __syncthreads();

    // ---- coalesced copy-out: 4096 chunks of 4 shorts (8 B), 256 threads x 16 iters ----
    const int limit = (j0 + 64 <= W1N) ? 64 : (W1N - j0);   // 64, or 60 at jt==3
    for (int it2 = 0; it2 < 16; ++it2) {
        int cc = it2 * 256 + tid;     // 0..4095
        int e  = cc * 4;              // element index in [c1][w][j]
        int c1 = e >> 8;
        int w2 = (e >> 6) & 3;
        int jb = e & 63;
        if (jb < limit) {
            int jr = (jb + (((c1 >> 2) & 3) << 4)) & 63;
            *(uint2*)(xbf + (size_t)b * KCNN + (c1 * H1N + i0 + w2) * W1N + j0 + jb) =
                *(const uint2*)(stg + (c1 * 4 + w2) * 64 + jr);
        }
    }
}

// ---------------- K2: barrier-free MFMA split-K GEMM -> atomic gacc[b][f] ----------------
// gacc[b][f] = sum_k x[b,k]*wr[f,k]. 756 blocks x 4 waves = 3024 waves (~12/CU, even
// spread vs the old 252-block grid that left 4 CUs idle at ~2 waves/SIMD). Each wave owns
// a private 192-k slice; per 32-k chunk: 2 A-loads (x bf16) + 6 B-loads (wr f32->bf16)
// + 6 MFMA. No __syncthreads in the k-loop; 2-deep register pipeline.
__global__ __launch_bounds__(256) void k2_gemm(
        const unsigned short* __restrict__ xbf, const float* __restrict__ wr,
        float* __restrict__ gacc) {
    __shared__ float red[4][32][41];  // wave-partials, stride 41 breaks 4-way conflicts

    const int tid  = threadIdx.x;
    const int wv   = tid >> 6;
    const int lane = tid & 63;
    const int l15  = lane & 15;
    const int quad = lane >> 4;
    const size_t kw = (size_t)(blockIdx.x * 4 + wv) * KPW;

    const unsigned short* ap0 = xbf + (size_t)l15 * KCNN + kw + quad * 8;
    const unsigned short* ap1 = ap0 + (size_t)16 * KCNN;
    const float* bp0 = wr + (size_t)l15 * KCNN + kw + quad * 8;
    const float* bp1 = bp0 + (size_t)16 * KCNN;
    const bool v2 = (l15 < 8);
    const float* bp2 = bp0 + (size_t)32 * KCNN;   // only dereferenced when v2

    f32x4 acc[2][3];
    #pragma unroll
    for (int mt = 0; mt < 2; ++mt)
        #pragma unroll
        for (int nt = 0; nt < 3; ++nt)
            acc[mt][nt] = (f32x4){0.f, 0.f, 0.f, 0.f};

    const float4 fz = {0.f, 0.f, 0.f, 0.f};
    bf16x8 a0c, a1c, a0n, a1n;
    float4 bw[3][2], bwn[3][2];

    // preload chunk 0
    a0c = *(const bf16x8*)ap0;
    a1c = *(const bf16x8*)ap1;
    bw[0][0] = *(const float4*)bp0; bw[0][1] = *(const float4*)(bp0 + 4);
    bw[1][0] = *(const float4*)bp1; bw[1][1] = *(const float4*)(bp1 + 4);
    if (v2) { bw[2][0] = *(const float4*)bp2; bw[2][1] = *(const float4*)(bp2 + 4); }
    else    { bw[2][0] = fz; bw[2][1] = fz; }

    for (int c = 0; c < 6; ++c) {
        if (c < 5) {                  // issue next chunk's loads; overlap with MFMA below
            const int o2 = (c + 1) * 32;
            a0n = *(const bf16x8*)(ap0 + o2);
            a1n = *(const bf16x8*)(ap1 + o2);
            bwn[0][0] = *(const float4*)(bp0 + o2); bwn[0][1] = *(const float4*)(bp0 + o2 + 4);
            bwn[1][0] = *(const float4*)(bp1 + o2); bwn[1][1] = *(const float4*)(bp1 + o2 + 4);
            if (v2) { bwn[2][0] = *(const float4*)(bp2 + o2); bwn[2][1] = *(const float4*)(bp2 + o2 + 4); }
            else    { bwn[2][0] = fz; bwn[2][1] = fz; }
        }
        #pragma unroll
        for (int nt = 0; nt < 3; ++nt) {
            bf16x8 bfrag = packbf(bw[nt][0], bw[nt][1]);
            acc[0][nt] = __builtin_amdgcn_mfma_f32_16x16x32_bf16(a0c, bfrag, acc[0][nt], 0, 0, 0);
            acc[1][nt] = __builtin_amdgcn_mfma_f32_16x16x32_bf16(a1c, bfrag, acc[1][nt], 0, 0, 0);
        }
        if (c < 5) {
            a0c = a0n; a1c = a1n;
            #pragma unroll
            for (int nt = 0; nt < 3; ++nt) { bw[nt][0] = bwn[nt][0]; bw[nt][1] = bwn[nt][1]; }
        }
    }

    // ---- reduce 4 waves via LDS, then atomics ----
    #pragma unroll
    for (int mt = 0; mt < 2; ++mt)
        #pragma unroll
        for (int nt = 0; nt < 3; ++nt)
            #pragma unroll
            for (int rg = 0; rg < 4; ++rg) {
                int bb = mt * 16 + quad * 4 + rg;
                int ff = nt * 16 + l15;
                if (ff < NF) red[wv][bb][ff] = acc[mt][nt][rg];
            }
    __syncthreads();
    for (int p = tid; p < 1280; p += 256) {
        int bb = p / 40, ff = p - bb * 40;
        float s = 0.0f;
        #pragma unroll
        for (int w = 0; w < 4; ++w) s += red[w][bb][ff];
        atomicAdd(gacc + p, s);
    }
}

// ---------------- K3: gates = sigmoid(gacc + br); wave-reduced wtd_mean atomic ----------
__global__ void k3_gates(const float* __restrict__ gacc, const float* __restrict__ br,
                         float* __restrict__ gates, float* __restrict__ out) {
    int p = blockIdx.x * 64 + threadIdx.x;    // 20 blocks -> 1280
    int f = p % 40;
    float g = 1.0f / (1.0f + __expf(-(gacc[p] + br[f])));
    gates[p] = g;
    float c = g * (2.0f * (float)(f + 1)) * (1.0f / 1280.0f);
    #pragma unroll
    for (int off = 32; off >= 1; off >>= 1)   // wave64 reduce -> 1 atomic/wave (was 64)
        c += __shfl_down(c, off, 64);
    if (threadIdx.x == 0) atomicAdd(out + 51200, c);
}

// ---------------- K4: feats (inline) -> sin/cos projection -> mods ----------------
__global__ __launch_bounds__(320) void k4_mods(
        const float* __restrict__ inp, const float* __restrict__ wf,
        const float* __restrict__ bfp, const float* __restrict__ gates,
        float* __restrict__ out) {
    const int f = blockIdx.x, b = blockIdx.y;
    const int tid = threadIdx.x;
    const int h  = tid >> 3;
    const int wl = tid & 7;
    float wfv[5];
    #pragma unroll
    for (int t = 0; t < 5; ++t) wfv[t] = wf[t];
    const float bias = bfp[0];
    const float cph = 6.283185307179586f * (float)(f + 1) / 255.0f;
    const float* row = inp + (b * HH + h) * WW;
    float sa = 0.0f, ca = 0.0f;
    for (int m = 0; m < 32; ++m) {
        int w = wl + 8 * m;
        float feat = bias;
        #pragma unroll
        for (int d = -2; d <= 2; ++d) {
            int wc = w + d;
            if (wc >= 0 && wc < WW) feat = fmaf(row[wc], wfv[d + 2], feat);
        }
        float sv, cv;
        __sincosf(cph * (float)w, &sv, &cv);
        sa = fmaf(sv, feat, sa);
        ca = fmaf(cv, feat, ca);
    }
    #pragma unroll
    for (int off = 4; off >= 1; off >>= 1) {
        sa += __shfl_xor(sa, off, 8);
        ca += __shfl_xor(ca, off, 8);
    }
    if (wl == 0) {
        float mag = sqrtf(sa * sa + ca * ca) * (1.0f / 256.0f);
        out[b * 1600 + f * 40 + h] = mag * gates[b * 40 + f];
    }
}

extern "C" void kernel_launch(void* const* d_in, const int* in_sizes, int n_in,
                              void* d_out, int out_size, void* d_ws, size_t ws_size,
                              hipStream_t stream) {
    const float* inp = (const float*)d_in[0];
    const float* w0  = (const float*)d_in[1];
    const float* b0  = (const float*)d_in[2];
    const float* w1  = (const float*)d_in[3];
    const float* b1  = (const float*)d_in[4];
    const float* wf  = (const float*)d_in[5];
    const float* bf_ = (const float*)d_in[6];
    const float* wr  = (const float*)d_in[7];
    const float* br  = (const float*)d_in[8];
    float* out = (float*)d_out;

    char* ws = (char*)d_ws;
    unsigned short* xbf = (unsigned short*)ws;               // 37,158,912 B
    unsigned short* w1c = (unsigned short*)(ws + 37158912);  // 36,864 B
    float* gacc  = (float*)(ws + 37195776);                  // 5,120 B
    float* gates = (float*)(ws + 37200896);                  // 5,120 B

    k0_prep_w1<<<72, 256, 0, stream>>>(w1, w1c, gacc, out);
    k1_conv<<<dim3(4, 9, 32), 256, 0, stream>>>(inp, w0, b0, w1c, b1, xbf);
    k2_gemm<<<756, 256, 0, stream>>>(xbf, wr, gacc);
    k3_gates<<<20, 64, 0, stream>>>(gacc, br, gates, out);
    k4_mods<<<dim3(40, 32), 320, 0, stream>>>(inp, wf, bf_, gates, out);
}